// Round 2
// baseline (1810.051 us; speedup 1.0000x reference)
//
#include <hip/hip_runtime.h>

// Problem: seq2seq LSTM. T=200 enc steps, DEC=30 dec steps, B=4096, H=100, IN=OUT=4.
// Strategy: persistent batch-parallel kernel. 256 blocks x 16 rows. All 230 steps
// inside one kernel; only block-local barriers. W^T (k-major) in LDS (k<98),
// k=98..103 (incl. x-part) in registers. c-state in registers. fp32 throughout.

#define NBLOCKS  256
#define NTHREADS 512
#define BR       16          // batch rows per block
#define KLDS     98          // k rows of W^T kept in LDS
#define KDIM     104         // H(100) + IN(4)

// ws layout (floats)
#define WS_WENC  0           // [104][400] enc W^T  (rows 0..99 = W_hh^T, 100..103 = W_ih^T)
#define WS_WDEC  41600       // [104][400] dec W^T
#define WS_BENC  83200       // [400] b_ih+b_hh enc
#define WS_BDEC  83600       // [400] dec

__global__ void prep_kernel(const float* __restrict__ Wih_e, const float* __restrict__ Whh_e,
                            const float* __restrict__ bih_e, const float* __restrict__ bhh_e,
                            const float* __restrict__ Wih_d, const float* __restrict__ Whh_d,
                            const float* __restrict__ bih_d, const float* __restrict__ bhh_d,
                            float* __restrict__ ws)
{
    for (int i = blockIdx.x * blockDim.x + threadIdx.x; i < 41600; i += gridDim.x * blockDim.x) {
        int k = i / 400, col = i - k * 400;
        ws[WS_WENC + i] = (k < 100) ? Whh_e[col * 100 + k] : Wih_e[col * 4 + (k - 100)];
        ws[WS_WDEC + i] = (k < 100) ? Whh_d[col * 100 + k] : Wih_d[col * 4 + (k - 100)];
        if (i < 400) {
            ws[WS_BENC + i] = bih_e[i] + bhh_e[i];
            ws[WS_BDEC + i] = bih_d[i] + bhh_d[i];
        }
    }
}

__device__ __forceinline__ float sigf(float x)  { return 1.f / (1.f + __expf(-x)); }
__device__ __forceinline__ float tanhx(float x) { return 1.f - 2.f / (__expf(2.f * x) + 1.f); }

// NOTE: macro params must NOT be named 'w'/'x'/'y'/'z' — they'd collide with
// the float4 member tokens after textual expansion (round-1 compile failure).
#define ACC4(a, wv, hs) { (a).x = fmaf((wv).x,(hs),(a).x); (a).y = fmaf((wv).y,(hs),(a).y); \
                          (a).z = fmaf((wv).z,(hs),(a).z); (a).w = fmaf((wv).w,(hs),(a).w); }

// Gate matvec for this thread's 4 consecutive j-columns of each gate (i,f,g,o).
#define GATE_LOOP()                                                              \
    do {                                                                         \
        _Pragma("unroll 2")                                                      \
        for (int k = 0; k < KLDS; ++k) {                                         \
            float hk = hrow[k];                                                  \
            const float* wk = &WT[k * 400 + jb];                                 \
            float4 w0 = *(const float4*)(wk);                                    \
            float4 w1 = *(const float4*)(wk + 100);                              \
            float4 w2 = *(const float4*)(wk + 200);                              \
            float4 w3 = *(const float4*)(wk + 300);                              \
            ACC4(a0, w0, hk) ACC4(a1, w1, hk) ACC4(a2, w2, hk) ACC4(a3, w3, hk)  \
        }                                                                        \
        _Pragma("unroll")                                                        \
        for (int kk = 0; kk < 6; ++kk) {                                         \
            float hk = hrow[KLDS + kk];                                          \
            ACC4(a0, wtail[kk][0], hk) ACC4(a1, wtail[kk][1], hk)                \
            ACC4(a2, wtail[kk][2], hk) ACC4(a3, wtail[kk][3], hk)                \
        }                                                                        \
    } while (0)

#define CELL_UPDATE(hn)                                                          \
    do {                                                                         \
        cc.x = sigf(a1.x) * cc.x + sigf(a0.x) * tanhx(a2.x);                     \
        cc.y = sigf(a1.y) * cc.y + sigf(a0.y) * tanhx(a2.y);                     \
        cc.z = sigf(a1.z) * cc.z + sigf(a0.z) * tanhx(a2.z);                     \
        cc.w = sigf(a1.w) * cc.w + sigf(a0.w) * tanhx(a2.w);                     \
        (hn).x = sigf(a3.x) * tanhx(cc.x);                                       \
        (hn).y = sigf(a3.y) * tanhx(cc.y);                                       \
        (hn).z = sigf(a3.z) * tanhx(cc.z);                                       \
        (hn).w = sigf(a3.w) * tanhx(cc.w);                                       \
    } while (0)

__global__ __launch_bounds__(NTHREADS) void seq2seq_kernel(
    const float* __restrict__ inputs,   // [200][4096][4]
    const float* __restrict__ ws,
    const float* __restrict__ Wy,       // [4][100]
    const float* __restrict__ by_g,     // [4]
    float* __restrict__ out)            // [30][4096][4]
{
    __shared__ __align__(16) float WT[KLDS * 400];   // 156800 B
    __shared__ __align__(16) float hx[BR][KDIM];     // 6656 B  (h | x/y_prev)

    const int tid  = threadIdx.x;
    const int grp  = tid >> 5;           // 0..15 -> row within block
    const int lane = tid & 31;
    const int row  = blockIdx.x * BR + grp;
    const int jb   = lane * 4;           // j base (lane<25 active: j=jb..jb+3)
    const bool act = (lane < 25);
    float* hrow = hx[grp];

    // stage encoder weights
    for (int i = tid; i < KLDS * 400; i += NTHREADS) WT[i] = ws[WS_WENC + i];
    for (int i = tid; i < BR * KDIM; i += NTHREADS) (&hx[0][0])[i] = 0.f;

    float4 wtail[6][4];                  // k=98..103 weight cols, in regs
    float4 bias[4];
    if (act) {
        #pragma unroll
        for (int kk = 0; kk < 6; ++kk)
            #pragma unroll
            for (int g = 0; g < 4; ++g)
                wtail[kk][g] = *(const float4*)&ws[WS_WENC + (KLDS + kk) * 400 + g * 100 + jb];
        #pragma unroll
        for (int g = 0; g < 4; ++g)
            bias[g] = *(const float4*)&ws[WS_BENC + g * 100 + jb];
    }
    float4 cc = make_float4(0.f, 0.f, 0.f, 0.f);

    // ---------------- encoder: 200 steps ----------------
    for (int step = 0; step < 200; ++step) {
        if (lane == 25)
            *(float4*)&hrow[100] = *(const float4*)&inputs[(step * 4096 + row) * 4];
        __syncthreads();                 // x visible, prev h fully written
        float4 a0 = bias[0], a1 = bias[1], a2 = bias[2], a3 = bias[3];
        if (act) GATE_LOOP();
        __syncthreads();                 // all h reads done before overwrite
        if (act) {
            float4 hn;
            CELL_UPDATE(hn);
            *(float4*)&hrow[jb] = hn;
        }
    }

    // ---------------- switch to decoder ----------------
    for (int i = tid; i < KLDS * 400; i += NTHREADS) WT[i] = ws[WS_WDEC + i];
    if (act) {
        #pragma unroll
        for (int kk = 0; kk < 6; ++kk)
            #pragma unroll
            for (int g = 0; g < 4; ++g)
                wtail[kk][g] = *(const float4*)&ws[WS_WDEC + (KLDS + kk) * 400 + g * 100 + jb];
        #pragma unroll
        for (int g = 0; g < 4; ++g)
            bias[g] = *(const float4*)&ws[WS_BDEC + g * 100 + jb];
    }
    float4 wy0, wy1, wy2, wy3;
    if (act) {
        wy0 = *(const float4*)&Wy[0 * 100 + jb];
        wy1 = *(const float4*)&Wy[1 * 100 + jb];
        wy2 = *(const float4*)&Wy[2 * 100 + jb];
        wy3 = *(const float4*)&Wy[3 * 100 + jb];
    }
    const float4 by = *(const float4*)by_g;
    if (lane == 25)                      // y_prev = 0
        *(float4*)&hrow[100] = make_float4(0.f, 0.f, 0.f, 0.f);
    cc = make_float4(0.f, 0.f, 0.f, 0.f);   // c reset for decoder

    // ---------------- decoder: 30 autoregressive steps ----------------
    for (int step = 0; step < 30; ++step) {
        __syncthreads();                 // WT reload / h,y writes visible
        float4 a0 = bias[0], a1 = bias[1], a2 = bias[2], a3 = bias[3];
        if (act) GATE_LOOP();
        __syncthreads();
        float4 hn = make_float4(0.f, 0.f, 0.f, 0.f);
        float p0 = 0.f, p1 = 0.f, p2 = 0.f, p3 = 0.f;
        if (act) {
            CELL_UPDATE(hn);
            *(float4*)&hrow[jb] = hn;
            p0 = wy0.x * hn.x + wy0.y * hn.y + wy0.z * hn.z + wy0.w * hn.w;
            p1 = wy1.x * hn.x + wy1.y * hn.y + wy1.z * hn.z + wy1.w * hn.w;
            p2 = wy2.x * hn.x + wy2.y * hn.y + wy2.z * hn.z + wy2.w * hn.w;
            p3 = wy3.x * hn.x + wy3.y * hn.y + wy3.z * hn.z + wy3.w * hn.w;
        }
        #pragma unroll
        for (int m = 16; m >= 1; m >>= 1) {
            p0 += __shfl_xor(p0, m, 32);
            p1 += __shfl_xor(p1, m, 32);
            p2 += __shfl_xor(p2, m, 32);
            p3 += __shfl_xor(p3, m, 32);
        }
        if (lane == 0) {
            float4 y = make_float4(p0 + by.x, p1 + by.y, p2 + by.z, p3 + by.w);
            *(float4*)&out[(step * 4096 + row) * 4] = y;
            *(float4*)&hrow[100] = y;    // y feeds back as next input
        }
    }
}

extern "C" void kernel_launch(void* const* d_in, const int* in_sizes, int n_in,
                              void* d_out, int out_size, void* d_ws, size_t ws_size,
                              hipStream_t stream)
{
    (void)in_sizes; (void)n_in; (void)out_size; (void)ws_size;
    const float* inputs = (const float*)d_in[0];
    const float* Wih_e  = (const float*)d_in[1];
    const float* Whh_e  = (const float*)d_in[2];
    const float* bih_e  = (const float*)d_in[3];
    const float* bhh_e  = (const float*)d_in[4];
    const float* Wih_d  = (const float*)d_in[5];
    const float* Whh_d  = (const float*)d_in[6];
    const float* bih_d  = (const float*)d_in[7];
    const float* bhh_d  = (const float*)d_in[8];
    const float* Wy     = (const float*)d_in[9];
    const float* by     = (const float*)d_in[10];
    float* out = (float*)d_out;
    float* ws  = (float*)d_ws;

    hipLaunchKernelGGL(prep_kernel, dim3(168), dim3(256), 0, stream,
                       Wih_e, Whh_e, bih_e, bhh_e, Wih_d, Whh_d, bih_d, bhh_d, ws);
    hipLaunchKernelGGL(seq2seq_kernel, dim3(NBLOCKS), dim3(NTHREADS), 0, stream,
                       inputs, ws, Wy, by, out);
}

// Round 3
// 395.926 us; speedup vs baseline: 4.5717x; 4.5717x over previous
//
#include <hip/hip_runtime.h>

// Seq2seq LSTM, MFMA-bf16 gate GEMM version.
// Per block: 16 batch rows. Per step: G[16][400] = hx[16][128pad] @ WT[128][400]
// via mfma_f32_16x16x32_bf16. B-fragments (weights) pre-built in ws by prep
// kernel and held in VGPRs. LDS: hx bf16 [16][136] + gate buf fp32 [16][404].
// Gate columns interleaved n = 4*j + gate so one b128 read gives (i,f,g,o).

#define NTHREADS 512

typedef __attribute__((ext_vector_type(8))) short short8;
typedef __attribute__((ext_vector_type(4))) float f32x4;

// ws layout: fragE ushort[51200] @0, fragD ushort[51200] @51200 (elem idx),
// biasE float[400] @byte 204800, biasD float[400] after it.
#define FRAG_ELEMS 51200
#define BIAS_BYTE_OFF 204800

__device__ __forceinline__ unsigned short f2bf(float f) {
    unsigned int u = __float_as_uint(f);
    unsigned int r = (u + 0x7fff + ((u >> 16) & 1)) >> 16;   // RNE
    return (unsigned short)r;
}
__device__ __forceinline__ float bf2f(unsigned short s) {
    return __uint_as_float(((unsigned int)s) << 16);
}
__device__ __forceinline__ float sigf(float x)  { return 1.f / (1.f + __expf(-x)); }
__device__ __forceinline__ float tanhx(float x) { return 1.f - 2.f / (__expf(2.f * x) + 1.f); }

// Build B-fragments: frag[((t*4+s)*64 + lane)*8 + e] = WT'[k][n] bf16, where
// k = s*32 + (lane>>4)*8 + e, n = t*16 + (lane&15), n = 4*jcol + gate,
// WT'[k][n] = (k<100) ? Whh[gate*100+jcol][k] : (k<104) ? Wih[gate*100+jcol][k-100] : 0
__global__ void prep_kernel(const float* __restrict__ Wih_e, const float* __restrict__ Whh_e,
                            const float* __restrict__ bih_e, const float* __restrict__ bhh_e,
                            const float* __restrict__ Wih_d, const float* __restrict__ Whh_d,
                            const float* __restrict__ bih_d, const float* __restrict__ bhh_d,
                            void* __restrict__ ws)
{
    unsigned short* frag = (unsigned short*)ws;
    float* bias = (float*)((char*)ws + BIAS_BYTE_OFF);
    int gid = blockIdx.x * blockDim.x + threadIdx.x;
    int gsz = gridDim.x * blockDim.x;
    for (int i = gid; i < 2 * FRAG_ELEMS; i += gsz) {
        int which = i / FRAG_ELEMS;
        int e = i - which * FRAG_ELEMS;
        int j8 = e & 7, lane = (e >> 3) & 63, s = (e >> 9) & 3, t = e >> 11;
        int k = s * 32 + (lane >> 4) * 8 + j8;
        int n = t * 16 + (lane & 15);
        int jcol = n >> 2, gate = n & 3, col = gate * 100 + jcol;
        const float* Whh = which ? Whh_d : Whh_e;
        const float* Wih = which ? Wih_d : Wih_e;
        float v = 0.f;
        if (k < 100)      v = Whh[col * 100 + k];
        else if (k < 104) v = Wih[col * 4 + (k - 100)];
        frag[i] = f2bf(v);
    }
    for (int i = gid; i < 800; i += gsz) {
        int which = i / 400, n = i - which * 400;
        int jcol = n >> 2, gate = n & 3, col = gate * 100 + jcol;
        bias[i] = which ? (bih_d[col] + bhh_d[col]) : (bih_e[col] + bhh_e[col]);
    }
}

__global__ __launch_bounds__(NTHREADS) void seq2seq_kernel(
    const float* __restrict__ inputs,   // [200][4096][4]
    const void* __restrict__ ws,
    const float* __restrict__ Wy,       // [4][100]
    const float* __restrict__ by_g,     // [4]
    float* __restrict__ out)            // [30][4096][4]
{
    __shared__ unsigned short A_lds[16 * 136];   // hx bf16, row stride 136 (bank-spread)
    __shared__ float G_lds[16 * 404];            // gates fp32, row stride 404

    const unsigned short* fragE = (const unsigned short*)ws;
    const unsigned short* fragD = fragE + FRAG_ELEMS;
    const float* biasE = (const float*)((const char*)ws + BIAS_BYTE_OFF);
    const float* biasD = biasE + 400;

    const int tid = threadIdx.x;
    const int wid = tid >> 6;          // wave 0..7
    const int wl  = tid & 63;
    const int m   = wl & 15;           // MFMA row (A) / col (C)
    const int q   = wl >> 4;           // lane quarter
    const int blk = blockIdx.x;

    // zero A (incl. K-pad cols 104..135)
    for (int i = tid; i < 16 * 136; i += NTHREADS) A_lds[i] = 0;

    float cst[4] = {0.f, 0.f, 0.f, 0.f};          // c state, cells tid+512*i

    // x-writer threads: tid 448..511 -> (row, comp)
    const bool isx = (tid >= 448);
    const int xu = tid - 448, xr = xu >> 2, xc = xu & 3;
    const float* xsrc = inputs + ((size_t)blk * 16 + xr) * 4 + xc;  // + step*16384

    // load encoder B-fragments + biases into regs
    short8 bfr[4][4];
    float breg[4] = {0.f, 0.f, 0.f, 0.f};
    #pragma unroll
    for (int i = 0; i < 4; ++i) {
        int t = wid + 8 * i;
        if (t < 25) {
            #pragma unroll
            for (int s = 0; s < 4; ++s)
                bfr[i][s] = *(const short8*)&fragE[((t * 4 + s) * 64 + wl) * 8];
            breg[i] = biasE[t * 16 + m];
        }
    }

    float xreg = isx ? xsrc[0] : 0.f;            // x_0
    __syncthreads();                             // A zero-init complete
    if (isx) {
        A_lds[xr * 136 + 100 + xc] = f2bf(xreg);
        xreg = xsrc[16384];                      // x_1
    }

    // ---------------- encoder: 200 steps ----------------
    for (int step = 0; step < 200; ++step) {
        __syncthreads();                         // A (h,x) ready
        short8 af[4];
        #pragma unroll
        for (int s = 0; s < 4; ++s)
            af[s] = *(const short8*)&A_lds[m * 136 + s * 32 + q * 8];
        #pragma unroll
        for (int i = 0; i < 4; ++i) {
            int t = wid + 8 * i;
            if (t < 25) {
                f32x4 acc = {breg[i], breg[i], breg[i], breg[i]};
                #pragma unroll
                for (int s = 0; s < 4; ++s)
                    acc = __builtin_amdgcn_mfma_f32_16x16x32_bf16(af[s], bfr[i][s], acc, 0, 0, 0);
                #pragma unroll
                for (int r = 0; r < 4; ++r)
                    G_lds[(q * 4 + r) * 404 + t * 16 + m] = acc[r];
            }
        }
        __syncthreads();                         // G ready, A reads done
        #pragma unroll
        for (int i = 0; i < 4; ++i) {
            int c = tid + NTHREADS * i;
            if (c < 1600) {
                int r = c & 15, j = c >> 4;
                f32x4 g = *(const f32x4*)&G_lds[r * 404 + 4 * j];
                float cn = sigf(g[1]) * cst[i] + sigf(g[0]) * tanhx(g[2]);
                cst[i] = cn;
                A_lds[r * 136 + j] = f2bf(sigf(g[3]) * tanhx(cn));
            }
        }
        if (isx && step < 199) {
            A_lds[xr * 136 + 100 + xc] = f2bf(xreg);
            if (step < 198) xreg = xsrc[(size_t)(step + 2) * 16384];
        }
    }

    // ---------------- switch to decoder ----------------
    #pragma unroll
    for (int i = 0; i < 4; ++i) {
        int t = wid + 8 * i;
        if (t < 25) {
            #pragma unroll
            for (int s = 0; s < 4; ++s)
                bfr[i][s] = *(const short8*)&fragD[((t * 4 + s) * 64 + wl) * 8];
            breg[i] = biasD[t * 16 + m];
        }
        cst[i] = 0.f;
    }
    if (isx) A_lds[xr * 136 + 100 + xc] = 0;     // y_prev = 0
    // y-projection thread mapping: 32 threads per row
    const int yrow = tid >> 5, yln = tid & 31;
    float wyr[4][4];
    #pragma unroll
    for (int o = 0; o < 4; ++o)
        #pragma unroll
        for (int i = 0; i < 4; ++i) {
            int j = yln + 32 * i;
            wyr[o][i] = (j < 100) ? Wy[o * 100 + j] : 0.f;
        }
    const float4 byv = *(const float4*)by_g;

    // ---------------- decoder: 30 autoregressive steps ----------------
    for (int step = 0; step < 30; ++step) {
        __syncthreads();                         // A (h,y) ready
        short8 af[4];
        #pragma unroll
        for (int s = 0; s < 4; ++s)
            af[s] = *(const short8*)&A_lds[m * 136 + s * 32 + q * 8];
        #pragma unroll
        for (int i = 0; i < 4; ++i) {
            int t = wid + 8 * i;
            if (t < 25) {
                f32x4 acc = {breg[i], breg[i], breg[i], breg[i]};
                #pragma unroll
                for (int s = 0; s < 4; ++s)
                    acc = __builtin_amdgcn_mfma_f32_16x16x32_bf16(af[s], bfr[i][s], acc, 0, 0, 0);
                #pragma unroll
                for (int r = 0; r < 4; ++r)
                    G_lds[(q * 4 + r) * 404 + t * 16 + m] = acc[r];
            }
        }
        __syncthreads();                         // G ready
        #pragma unroll
        for (int i = 0; i < 4; ++i) {
            int c = tid + NTHREADS * i;
            if (c < 1600) {
                int r = c & 15, j = c >> 4;
                f32x4 g = *(const f32x4*)&G_lds[r * 404 + 4 * j];
                float cn = sigf(g[1]) * cst[i] + sigf(g[0]) * tanhx(g[2]);
                cst[i] = cn;
                A_lds[r * 136 + j] = f2bf(sigf(g[3]) * tanhx(cn));
            }
        }
        __syncthreads();                         // h complete
        float p0 = 0.f, p1 = 0.f, p2 = 0.f, p3 = 0.f;
        #pragma unroll
        for (int i = 0; i < 4; ++i) {
            int j = yln + 32 * i;
            if (j < 100) {
                float hv = bf2f(A_lds[yrow * 136 + j]);
                p0 = fmaf(wyr[0][i], hv, p0);
                p1 = fmaf(wyr[1][i], hv, p1);
                p2 = fmaf(wyr[2][i], hv, p2);
                p3 = fmaf(wyr[3][i], hv, p3);
            }
        }
        #pragma unroll
        for (int mm = 16; mm >= 1; mm >>= 1) {
            p0 += __shfl_xor(p0, mm, 32);
            p1 += __shfl_xor(p1, mm, 32);
            p2 += __shfl_xor(p2, mm, 32);
            p3 += __shfl_xor(p3, mm, 32);
        }
        if (yln == 0) {
            float4 yv = make_float4(p0 + byv.x, p1 + byv.y, p2 + byv.z, p3 + byv.w);
            *(float4*)&out[((size_t)step * 4096 + blk * 16 + yrow) * 4] = yv;
            A_lds[yrow * 136 + 100 + 0] = f2bf(yv.x);
            A_lds[yrow * 136 + 100 + 1] = f2bf(yv.y);
            A_lds[yrow * 136 + 100 + 2] = f2bf(yv.z);
            A_lds[yrow * 136 + 100 + 3] = f2bf(yv.w);
        }
    }
}

extern "C" void kernel_launch(void* const* d_in, const int* in_sizes, int n_in,
                              void* d_out, int out_size, void* d_ws, size_t ws_size,
                              hipStream_t stream)
{
    (void)in_sizes; (void)n_in; (void)out_size; (void)ws_size;
    const float* inputs = (const float*)d_in[0];
    const float* Wih_e  = (const float*)d_in[1];
    const float* Whh_e  = (const float*)d_in[2];
    const float* bih_e  = (const float*)d_in[3];
    const float* bhh_e  = (const float*)d_in[4];
    const float* Wih_d  = (const float*)d_in[5];
    const float* Whh_d  = (const float*)d_in[6];
    const float* bih_d  = (const float*)d_in[7];
    const float* bhh_d  = (const float*)d_in[8];
    const float* Wy     = (const float*)d_in[9];
    const float* by     = (const float*)d_in[10];
    float* out = (float*)d_out;

    hipLaunchKernelGGL(prep_kernel, dim3(256), dim3(256), 0, stream,
                       Wih_e, Whh_e, bih_e, bhh_e, Wih_d, Whh_d, bih_d, bhh_d, d_ws);
    hipLaunchKernelGGL(seq2seq_kernel, dim3(256), dim3(NTHREADS), 0, stream,
                       inputs, d_ws, Wy, by, out);
}